// Round 8
// baseline (142.809 us; speedup 1.0000x reference)
//
#include <hip/hip_runtime.h>

typedef float    v2f __attribute__((ext_vector_type(2)));
typedef _Float16 v2h __attribute__((ext_vector_type(2)));

__device__ __forceinline__ float fexp2(float x) { return __builtin_amdgcn_exp2f(x); }
__device__ __forceinline__ float flog2(float x) { return __builtin_amdgcn_logf(x); }
__device__ __forceinline__ v2f  splat(float s) { v2f v; v.x = s; v.y = s; return v; }
__device__ __forceinline__ v2f  pkfma(v2f a, v2f b, v2f c) { return __builtin_elementwise_fma(a, b, c); }
__device__ __forceinline__ v2h  splath(float s) { v2h v; v.x = (_Float16)s; v.y = (_Float16)s; return v; }
__device__ __forceinline__ v2h  pkfmah(v2h a, v2h b, v2h c) { return __builtin_elementwise_fma(a, b, c); }
__device__ __forceinline__ v2h  cvt_pk(float a, float b) {
    return __builtin_bit_cast(v2h, __builtin_amdgcn_cvt_pkrtz(a, b));
}
// packed-pair helpers (elementwise over the two points)
__device__ __forceinline__ v2f pexp2(v2f e) { v2f r; r.x = fexp2(e.x); r.y = fexp2(e.y); return r; }
__device__ __forceinline__ v2f plog2(v2f e) { v2f r; r.x = flog2(e.x); r.y = flog2(e.y); return r; }
__device__ __forceinline__ v2f selgt(v2f c, float thr, v2f a, v2f b) {
    v2f r; r.x = c.x > thr ? a.x : b.x; r.y = c.y > thr ? a.y : b.y; return r;
}
__device__ __forceinline__ v2f selle(v2f c, float thr, v2f a, v2f b) {
    v2f r; r.x = c.x <= thr ? a.x : b.x; r.y = c.y <= thr ? a.y : b.y; return r;
}
__device__ __forceinline__ v2f pmax(v2f a, float s) { return __builtin_elementwise_max(a, splat(s)); }

#define LAB_EPS 0.008856f
#define F16_116 0.13793103448275862f   // 16/116
#define LOG2_10 3.3219280948873623f

// ---------------------------------------------------------------------------
// Single launch, ZERO LDS, ZERO barrier (r4's 47.2us body shape, single-launch).
//  - hidden loop: raw w_seq1/b_seq1/w_seq2 via loop-uniform float4 -> s_load
//    SGPR broadcast; w_seq2 -> half2 in-loop (cvt_pkrtz); H3 fold deferred.
//  - epilogue constants folded PER-THREAD from wave-uniform s_loaded weights
//    (~140 uniform VALU ops) — removes the r6/r7 prologue + __syncthreads +
//    LDS entirely; no block-level sync anywhere.
// ---------------------------------------------------------------------------
__global__ __launch_bounds__(256) void fused_kernel(
    const float* __restrict__ x,
    const float* __restrict__ w_seq1, const float* __restrict__ b_seq1,
    const float* __restrict__ w_seq2, const float* __restrict__ b_seq2,
    const float* __restrict__ w_lin,  const float* __restrict__ b_lin,
    const float* __restrict__ w_comb, const float* __restrict__ b_comb,
    const float* __restrict__ w_logd, const float* __restrict__ b_logd,
    const float* __restrict__ w_final,const float* __restrict__ b_final,
    float* __restrict__ out, int n)
{
    const int g = blockIdx.x * blockDim.x + threadIdx.x;
    if (g * 2 >= n) return;

    // 2 points = 6 floats = 3 float2 (coalesced 8B loads)
    const float2* xin = reinterpret_cast<const float2*>(x) + (size_t)g * 3;
    const float2 v0 = xin[0], v1 = xin[1], v2 = xin[2];
    // p0 = {v0.x, v0.y, v1.x}, p1 = {v1.y, v2.x, v2.y}
    v2f xs2[3];
    xs2[0].x = v0.x; xs2[0].y = v1.y;
    xs2[1].x = v0.y; xs2[1].y = v2.x;
    xs2[2].x = v1.x; xs2[2].y = v2.y;

    v2h acc0 = splath(0.f), acc1 = splath(0.f), acc2 = splath(0.f);

    // row i of w_seq1 at float4 offset i*16 + q; w_seq2 rows j0..j0+3 at 3q..3q+2
    const float4* __restrict__ w1v = reinterpret_cast<const float4*>(w_seq1);
    const float4* __restrict__ b1v = reinterpret_cast<const float4*>(b_seq1);
    const float4* __restrict__ w2v = reinterpret_cast<const float4*>(w_seq2);

    // Hidden layer, stage-major 4-wide batches; ALL weights via s_load.
    // tc = clamp(t,-3,3); u = tc^2; P cubic (max h-err ~0.02); h = tc*P.
#pragma unroll 2
    for (int j0 = 0; j0 < 64; j0 += 4) {
        const int q = j0 >> 2;
        const float4 wr0 = w1v[q];         // w_seq1[0][j0..j0+3]
        const float4 wr1 = w1v[16 + q];    // w_seq1[1][...]
        const float4 wr2 = w1v[32 + q];    // w_seq1[2][...]
        const float4 wrb = b1v[q];         // b_seq1[...]
        const float4 w2a = w2v[3 * q];     // w2[j0][0..2], w2[j0+1][0]
        const float4 w2b = w2v[3 * q + 1]; // w2[j0+1][1..2], w2[j0+2][0..1]
        const float4 w2c = w2v[3 * q + 2]; // w2[j0+2][2], w2[j0+3][0..2]

        v2f t0 = pkfma(xs2[0], splat(wr0.x), pkfma(xs2[1], splat(wr1.x), pkfma(xs2[2], splat(wr2.x), splat(wrb.x))));
        v2f t1 = pkfma(xs2[0], splat(wr0.y), pkfma(xs2[1], splat(wr1.y), pkfma(xs2[2], splat(wr2.y), splat(wrb.y))));
        v2f t2 = pkfma(xs2[0], splat(wr0.z), pkfma(xs2[1], splat(wr1.z), pkfma(xs2[2], splat(wr2.z), splat(wrb.z))));
        v2f t3 = pkfma(xs2[0], splat(wr0.w), pkfma(xs2[1], splat(wr1.w), pkfma(xs2[2], splat(wr2.w), splat(wrb.w))));

        v2h th0 = cvt_pk(t0.x, t0.y);
        v2h th1 = cvt_pk(t1.x, t1.y);
        v2h th2 = cvt_pk(t2.x, t2.y);
        v2h th3 = cvt_pk(t3.x, t3.y);

        const v2h hi3 = splath(3.0f), lo3 = splath(-3.0f);
        th0 = __builtin_elementwise_min(__builtin_elementwise_max(th0, lo3), hi3);
        th1 = __builtin_elementwise_min(__builtin_elementwise_max(th1, lo3), hi3);
        th2 = __builtin_elementwise_min(__builtin_elementwise_max(th2, lo3), hi3);
        th3 = __builtin_elementwise_min(__builtin_elementwise_max(th3, lo3), hi3);

        v2h u0 = th0 * th0, u1 = th1 * th1, u2 = th2 * th2, u3 = th3 * th3;

        const v2h c3 = splath(-0.00120984f), c2h = splath(0.02603622f);
        const v2h c1 = splath(-0.20598500f), c0h = splath(0.95858467f);
        v2h P0 = pkfmah(c3, u0, c2h);
        v2h P1 = pkfmah(c3, u1, c2h);
        v2h P2 = pkfmah(c3, u2, c2h);
        v2h P3 = pkfmah(c3, u3, c2h);
        P0 = pkfmah(P0, u0, c1);
        P1 = pkfmah(P1, u1, c1);
        P2 = pkfmah(P2, u2, c1);
        P3 = pkfmah(P3, u3, c1);
        P0 = pkfmah(P0, u0, c0h);
        P1 = pkfmah(P1, u1, c0h);
        P2 = pkfmah(P2, u2, c0h);
        P3 = pkfmah(P3, u3, c0h);

        v2h h0 = th0 * P0, h1 = th1 * P1, h2 = th2 * P2, h3 = th3 * P3;

        acc0 = pkfmah(h0, cvt_pk(w2a.x, w2a.x), acc0);
        acc1 = pkfmah(h0, cvt_pk(w2a.y, w2a.y), acc1);
        acc2 = pkfmah(h0, cvt_pk(w2a.z, w2a.z), acc2);
        acc0 = pkfmah(h1, cvt_pk(w2a.w, w2a.w), acc0);
        acc1 = pkfmah(h1, cvt_pk(w2b.x, w2b.x), acc1);
        acc2 = pkfmah(h1, cvt_pk(w2b.y, w2b.y), acc2);
        acc0 = pkfmah(h2, cvt_pk(w2b.z, w2b.z), acc0);
        acc1 = pkfmah(h2, cvt_pk(w2b.w, w2b.w), acc1);
        acc2 = pkfmah(h2, cvt_pk(w2c.x, w2c.x), acc2);
        acc0 = pkfmah(h3, cvt_pk(w2c.y, w2c.y), acc0);
        acc1 = pkfmah(h3, cvt_pk(w2c.z, w2c.z), acc1);
        acc2 = pkfmah(h3, cvt_pk(w2c.w, w2c.w), acc2);
    }

    // ---- Per-thread wave-uniform constant fold (inputs s_loaded -> SGPRs) ----
    float Wn[9], bl2[3];
#pragma unroll
    for (int i = 0; i < 9; ++i) Wn[i] = -w_logd[i];
#pragma unroll
    for (int i = 0; i < 3; ++i) bl2[i] = LOG2_10 * b_logd[i];

    float A[9], U[9], H3c[9], cv[3];
#pragma unroll
    for (int c = 0; c < 3; ++c) {
        const float wf0 = w_final[c], wf3 = w_final[3 + c], wf6 = w_final[6 + c];
        const float Gc0 = w_comb[0] * wf0 + w_comb[1] * wf3 + w_comb[2] * wf6;
        const float Gc1 = w_comb[3] * wf0 + w_comb[4] * wf3 + w_comb[5] * wf6;
        const float Gc2 = w_comb[6] * wf0 + w_comb[7] * wf3 + w_comb[8] * wf6;
        const float H30 = w_comb[ 9] * wf0 + w_comb[10] * wf3 + w_comb[11] * wf6;
        const float H31 = w_comb[12] * wf0 + w_comb[13] * wf3 + w_comb[14] * wf6;
        const float H32 = w_comb[15] * wf0 + w_comb[16] * wf3 + w_comb[17] * wf6;
        H3c[c]     = H30;
        H3c[3 + c] = H31;
        H3c[6 + c] = H32;
        A[c]     = w_lin[0] * Gc0 + w_lin[1] * Gc1 + w_lin[2] * Gc2;
        A[3 + c] = w_lin[3] * Gc0 + w_lin[4] * Gc1 + w_lin[5] * Gc2;
        A[6 + c] = w_lin[6] * Gc0 + w_lin[7] * Gc1 + w_lin[8] * Gc2;
        const float wb0 = w_final[9 + c], wb1 = w_final[12 + c], wb2 = w_final[15 + c];
        U[c]     = 500.0f * wb1;
        U[3 + c] = 116.0f * wb0 - 500.0f * wb1 + 200.0f * wb2;
        U[6 + c] = -200.0f * wb2;
        float s = b_final[c] - 16.0f * wb0;
        s += b_lin[0] * Gc0 + b_lin[1] * Gc1 + b_lin[2] * Gc2;
        s += b_seq2[0] * H30 + b_seq2[1] * H31 + b_seq2[2] * H32;
        s += b_comb[0] * wf0 + b_comb[1] * wf3 + b_comb[2] * wf6;
        cv[c] = s;
    }

    // ---- Epilogue, packed over the 2 points (v2f = {p0, p1}) ----
    v2f sm0, sm1, sm2;   // raw seq sums (pre-H3)
    sm0.x = (float)acc0.x; sm0.y = (float)acc0.y;
    sm1.x = (float)acc1.x; sm1.y = (float)acc1.y;
    sm2.x = (float)acc2.x; sm2.y = (float)acc2.y;

    // lab2rgb(x)
    const v2f fy = (xs2[0] + splat(16.0f)) * splat(1.0f / 116.0f);
    const v2f fx = pkfma(xs2[1], splat( 0.002f), fy);
    const v2f fz = pkfma(xs2[2], splat(-0.005f), fy);
    const v2f f3x = fx * fx * fx, f3y = fy * fy * fy, f3z = fz * fz * fz;
    const v2f tx = selgt(f3x, LAB_EPS, f3x, (fx - splat(F16_116)) * splat(1.0f / 7.787f));
    const v2f ty = selgt(f3y, LAB_EPS, f3y, (fy - splat(F16_116)) * splat(1.0f / 7.787f));
    const v2f tz = selgt(f3z, LAB_EPS, f3z, (fz - splat(F16_116)) * splat(1.0f / 7.787f));
    const v2f X = tx * splat(0.95047f), Y = ty, Z = tz * splat(1.08883f);
    v2f linv[3];
    linv[0] = pkfma(X, splat( 3.2404542f), pkfma(Y, splat(-1.5371385f), Z * splat(-0.4985314f)));
    linv[1] = pkfma(X, splat(-0.9692660f), pkfma(Y, splat( 1.8760108f), Z * splat( 0.0415560f)));
    linv[2] = pkfma(X, splat( 0.0556434f), pkfma(Y, splat(-0.2040259f), Z * splat( 1.0572252f)));
    v2f lg[3];
#pragma unroll
    for (int c = 0; c < 3; ++c) {
        const v2f cc = linv[c];
        const v2f lo = cc * splat(12.92f);
        const v2f hi = pkfma(pexp2(plog2(pmax(cc, 0.0031308f)) * splat(1.0f / 2.4f)),
                             splat(1.055f), splat(-0.055f));
        lg[c] = plog2(selle(cc, 0.0031308f, lo, hi));
    }
    // r10 = exp2(lg@Wn + bl2); srgb_to_linear(r10)
    v2f lin2[3];
#pragma unroll
    for (int c = 0; c < 3; ++c) {
        const v2f e   = pkfma(lg[0], splat(Wn[c]),
                        pkfma(lg[1], splat(Wn[3 + c]),
                        pkfma(lg[2], splat(Wn[6 + c]), splat(bl2[c]))));
        const v2f r10 = pexp2(e);
        const v2f lo  = r10 * splat(1.0f / 12.92f);
        const v2f base = (pmax(r10, 0.04045f) + splat(0.055f)) * splat(1.0f / 1.055f);
        const v2f hi  = pexp2(plog2(base) * splat(2.4f));
        lin2[c] = selle(r10, 0.04045f, lo, hi);
    }
    // rgb2lab -> f-values
    const v2f X2 = pkfma(lin2[0], splat(0.412453f), pkfma(lin2[1], splat(0.357580f), lin2[2] * splat(0.180423f))) * splat(1.0f / 0.95047f);
    const v2f Y2 = pkfma(lin2[0], splat(0.212671f), pkfma(lin2[1], splat(0.715160f), lin2[2] * splat(0.072169f)));
    const v2f Z2 = pkfma(lin2[0], splat(0.019334f), pkfma(lin2[1], splat(0.119193f), lin2[2] * splat(0.950227f))) * splat(1.0f / 1.08883f);
    const v2f fX = selgt(X2, LAB_EPS, pexp2(plog2(pmax(X2, LAB_EPS)) * splat(1.0f / 3.0f)), pkfma(X2, splat(7.787f), splat(F16_116)));
    const v2f fY = selgt(Y2, LAB_EPS, pexp2(plog2(pmax(Y2, LAB_EPS)) * splat(1.0f / 3.0f)), pkfma(Y2, splat(7.787f), splat(F16_116)));
    const v2f fZ = selgt(Z2, LAB_EPS, pexp2(plog2(pmax(Z2, LAB_EPS)) * splat(1.0f / 3.0f)), pkfma(Z2, splat(7.787f), splat(F16_116)));
    // final combine: cv + x@A + s@H3 + f@U
    v2f o[3];
#pragma unroll
    for (int c = 0; c < 3; ++c) {
        v2f oc = splat(cv[c]);
        oc = pkfma(xs2[0], splat(A[c]),       oc);
        oc = pkfma(xs2[1], splat(A[3 + c]),   oc);
        oc = pkfma(xs2[2], splat(A[6 + c]),   oc);
        oc = pkfma(sm0,    splat(H3c[c]),     oc);
        oc = pkfma(sm1,    splat(H3c[3 + c]), oc);
        oc = pkfma(sm2,    splat(H3c[6 + c]), oc);
        oc = pkfma(fX,     splat(U[c]),       oc);
        oc = pkfma(fY,     splat(U[3 + c]),   oc);
        oc = pkfma(fZ,     splat(U[6 + c]),   oc);
        o[c] = oc;
    }

    float2* op = reinterpret_cast<float2*>(out) + (size_t)g * 3;
    op[0] = make_float2(o[0].x, o[1].x);
    op[1] = make_float2(o[2].x, o[0].y);
    op[2] = make_float2(o[1].y, o[2].y);
}

extern "C" void kernel_launch(void* const* d_in, const int* in_sizes, int n_in,
                              void* d_out, int out_size, void* d_ws, size_t ws_size,
                              hipStream_t stream)
{
    const float* x       = (const float*)d_in[0];
    const float* w_seq1  = (const float*)d_in[1];
    const float* b_seq1  = (const float*)d_in[2];
    const float* w_seq2  = (const float*)d_in[3];
    const float* b_seq2  = (const float*)d_in[4];
    const float* w_lin   = (const float*)d_in[5];
    const float* b_lin   = (const float*)d_in[6];
    const float* w_comb  = (const float*)d_in[7];
    const float* b_comb  = (const float*)d_in[8];
    const float* w_logd  = (const float*)d_in[9];
    const float* b_logd  = (const float*)d_in[10];
    const float* w_final = (const float*)d_in[11];
    const float* b_final = (const float*)d_in[12];
    float* outp = (float*)d_out;

    const int n = in_sizes[0] / 3;            // 2,097,152 points
    const int threads = 256;
    const int total_threads = (n + 1) / 2;    // 2 points per thread
    const int blocks = (total_threads + threads - 1) / threads;

    fused_kernel<<<blocks, threads, 0, stream>>>(
        x, w_seq1, b_seq1, w_seq2, b_seq2, w_lin, b_lin, w_comb, b_comb,
        w_logd, b_logd, w_final, b_final, outp, n);
}

// Round 9
// 139.045 us; speedup vs baseline: 1.0271x; 1.0271x over previous
//
#include <hip/hip_runtime.h>

typedef float    v2f __attribute__((ext_vector_type(2)));
typedef _Float16 v2h __attribute__((ext_vector_type(2)));

__device__ __forceinline__ float fexp2(float x) { return __builtin_amdgcn_exp2f(x); }
__device__ __forceinline__ float flog2(float x) { return __builtin_amdgcn_logf(x); }
__device__ __forceinline__ v2f  splat(float s) { v2f v; v.x = s; v.y = s; return v; }
__device__ __forceinline__ v2f  pkfma(v2f a, v2f b, v2f c) { return __builtin_elementwise_fma(a, b, c); }
__device__ __forceinline__ v2h  splath(float s) { v2h v; v.x = (_Float16)s; v.y = (_Float16)s; return v; }
__device__ __forceinline__ v2h  pkfmah(v2h a, v2h b, v2h c) { return __builtin_elementwise_fma(a, b, c); }
__device__ __forceinline__ v2h  cvt_pk(float a, float b) {
    return __builtin_bit_cast(v2h, __builtin_amdgcn_cvt_pkrtz(a, b));
}
// lo/hi broadcast of a half2 — folds into VOP3P op_sel on the consuming pk_fma
__device__ __forceinline__ v2h blo(v2h v) { v2h r; r.x = v.x; r.y = v.x; return r; }
__device__ __forceinline__ v2h bhi(v2h v) { v2h r; r.x = v.y; r.y = v.y; return r; }
// packed-pair helpers (elementwise over the two points)
__device__ __forceinline__ v2f pexp2(v2f e) { v2f r; r.x = fexp2(e.x); r.y = fexp2(e.y); return r; }
__device__ __forceinline__ v2f plog2(v2f e) { v2f r; r.x = flog2(e.x); r.y = flog2(e.y); return r; }
__device__ __forceinline__ v2f selgt(v2f c, float thr, v2f a, v2f b) {
    v2f r; r.x = c.x > thr ? a.x : b.x; r.y = c.y > thr ? a.y : b.y; return r;
}
__device__ __forceinline__ v2f selle(v2f c, float thr, v2f a, v2f b) {
    v2f r; r.x = c.x <= thr ? a.x : b.x; r.y = c.y <= thr ? a.y : b.y; return r;
}
__device__ __forceinline__ v2f pmax(v2f a, float s) { return __builtin_elementwise_max(a, splat(s)); }

#define LAB_EPS 0.008856f
#define F16_116 0.13793103448275862f   // 16/116
#define LOG2_10 3.3219280948873623f

// ---------------------------------------------------------------------------
// Single launch, NO BARRIER (r8 post-mortem: per-thread fold = VALU disaster;
// r7 post-mortem: block barrier costs occupancy).
//  - WAVE-LOCAL fold: lanes 0-8 of EACH wave compute the 42 epilogue consts
//    and ds_write to a per-wave LDS slot BEFORE the hidden loop; readers are
//    the same wave, so ordinary lgkmcnt ordering suffices — no __syncthreads.
//    Writes issue ~2000cy ahead of the reads (hidden under the loop).
//  - hidden loop: raw w_seq1/b_seq1/w_seq2 via loop-uniform float4 -> s_load;
//    w_seq2 cvt count HALVED: cvt_pk(w2[j][m], w2[j+1][m]) packs two j's,
//    per-j broadcast via lo/hi shuffle -> VOP3P op_sel (free).
//  - H3 fold deferred to epilogue (r7 scheme, verified).
// ---------------------------------------------------------------------------
__global__ __launch_bounds__(256) void fused_kernel(
    const float* __restrict__ x,
    const float* __restrict__ w_seq1, const float* __restrict__ b_seq1,
    const float* __restrict__ w_seq2, const float* __restrict__ b_seq2,
    const float* __restrict__ w_lin,  const float* __restrict__ b_lin,
    const float* __restrict__ w_comb, const float* __restrict__ b_comb,
    const float* __restrict__ w_logd, const float* __restrict__ b_logd,
    const float* __restrict__ w_final,const float* __restrict__ b_final,
    float* __restrict__ out, int n)
{
    // per-wave constant slots: [A 0..8][U 9..17][Wn 18..26][bl2 27..29][cv 30..32][H3 33..41]
    __shared__ float smw[4][44];

    const int tid  = threadIdx.x;
    const int wid  = tid >> 6;
    const int lane = tid & 63;

    if (lane < 9) {
        const int kk = lane / 3, c = lane - kk * 3;
        float* sm = smw[wid];
        const float wf0 = w_final[c], wf3 = w_final[3 + c], wf6 = w_final[6 + c];
        const float Gc0 = w_comb[0] * wf0 + w_comb[1] * wf3 + w_comb[2] * wf6;
        const float Gc1 = w_comb[3] * wf0 + w_comb[4] * wf3 + w_comb[5] * wf6;
        const float Gc2 = w_comb[6] * wf0 + w_comb[7] * wf3 + w_comb[8] * wf6;
        sm[lane] = w_lin[kk * 3 + 0] * Gc0 + w_lin[kk * 3 + 1] * Gc1 + w_lin[kk * 3 + 2] * Gc2;   // A
        const float wb0 = w_final[9 + c], wb1 = w_final[12 + c], wb2 = w_final[15 + c];
        sm[9 + lane] = (kk == 0) ? 500.0f * wb1
                     : (kk == 1) ? 116.0f * wb0 - 500.0f * wb1 + 200.0f * wb2
                                 : -200.0f * wb2;                                                 // U
        sm[18 + lane] = -w_logd[lane];                                                            // Wn
        sm[33 + lane] = w_comb[(kk + 3) * 3 + 0] * wf0 + w_comb[(kk + 3) * 3 + 1] * wf3
                      + w_comb[(kk + 3) * 3 + 2] * wf6;                                           // H3
        if (kk == 0) {   // lane < 3, c == lane
            sm[27 + c] = LOG2_10 * b_logd[c];                                                     // bl2
            const float H30 = w_comb[ 9] * wf0 + w_comb[10] * wf3 + w_comb[11] * wf6;
            const float H31 = w_comb[12] * wf0 + w_comb[13] * wf3 + w_comb[14] * wf6;
            const float H32 = w_comb[15] * wf0 + w_comb[16] * wf3 + w_comb[17] * wf6;
            float s = b_final[c] - 16.0f * wb0;
            s += b_lin[0] * Gc0 + b_lin[1] * Gc1 + b_lin[2] * Gc2;
            s += b_seq2[0] * H30 + b_seq2[1] * H31 + b_seq2[2] * H32;
            s += b_comb[0] * wf0 + b_comb[1] * wf3 + b_comb[2] * wf6;
            sm[30 + c] = s;                                                                       // cv
        }
    }

    const int g = blockIdx.x * blockDim.x + tid;
    if (g * 2 >= n) return;     // n is a multiple of 512 in practice; guard only

    // 2 points = 6 floats = 3 float2 (coalesced 8B loads)
    const float2* xin = reinterpret_cast<const float2*>(x) + (size_t)g * 3;
    const float2 v0 = xin[0], v1 = xin[1], v2 = xin[2];
    // p0 = {v0.x, v0.y, v1.x}, p1 = {v1.y, v2.x, v2.y}
    v2f xs2[3];
    xs2[0].x = v0.x; xs2[0].y = v1.y;
    xs2[1].x = v0.y; xs2[1].y = v2.x;
    xs2[2].x = v1.x; xs2[2].y = v2.y;

    v2h acc0 = splath(0.f), acc1 = splath(0.f), acc2 = splath(0.f);

    // row i of w_seq1 at float4 offset i*16 + q; w_seq2 rows j0..j0+3 at 3q..3q+2
    const float4* __restrict__ w1v = reinterpret_cast<const float4*>(w_seq1);
    const float4* __restrict__ b1v = reinterpret_cast<const float4*>(b_seq1);
    const float4* __restrict__ w2v = reinterpret_cast<const float4*>(w_seq2);

    // Hidden layer, stage-major 4-wide batches; ALL weights via s_load.
    // tc = clamp(t,-3,3); u = tc^2; P cubic (max h-err ~0.02); h = tc*P.
#pragma unroll 2
    for (int j0 = 0; j0 < 64; j0 += 4) {
        const int q = j0 >> 2;
        const float4 wr0 = w1v[q];         // w_seq1[0][j0..j0+3]
        const float4 wr1 = w1v[16 + q];    // w_seq1[1][...]
        const float4 wr2 = w1v[32 + q];    // w_seq1[2][...]
        const float4 wrb = b1v[q];         // b_seq1[...]
        const float4 w2a = w2v[3 * q];     // w2[j0][0..2], w2[j0+1][0]
        const float4 w2b = w2v[3 * q + 1]; // w2[j0+1][1..2], w2[j0+2][0..1]
        const float4 w2c = w2v[3 * q + 2]; // w2[j0+2][2], w2[j0+3][0..2]

        v2f t0 = pkfma(xs2[0], splat(wr0.x), pkfma(xs2[1], splat(wr1.x), pkfma(xs2[2], splat(wr2.x), splat(wrb.x))));
        v2f t1 = pkfma(xs2[0], splat(wr0.y), pkfma(xs2[1], splat(wr1.y), pkfma(xs2[2], splat(wr2.y), splat(wrb.y))));
        v2f t2 = pkfma(xs2[0], splat(wr0.z), pkfma(xs2[1], splat(wr1.z), pkfma(xs2[2], splat(wr2.z), splat(wrb.z))));
        v2f t3 = pkfma(xs2[0], splat(wr0.w), pkfma(xs2[1], splat(wr1.w), pkfma(xs2[2], splat(wr2.w), splat(wrb.w))));

        v2h th0 = cvt_pk(t0.x, t0.y);
        v2h th1 = cvt_pk(t1.x, t1.y);
        v2h th2 = cvt_pk(t2.x, t2.y);
        v2h th3 = cvt_pk(t3.x, t3.y);

        const v2h hi3 = splath(3.0f), lo3 = splath(-3.0f);
        th0 = __builtin_elementwise_min(__builtin_elementwise_max(th0, lo3), hi3);
        th1 = __builtin_elementwise_min(__builtin_elementwise_max(th1, lo3), hi3);
        th2 = __builtin_elementwise_min(__builtin_elementwise_max(th2, lo3), hi3);
        th3 = __builtin_elementwise_min(__builtin_elementwise_max(th3, lo3), hi3);

        v2h u0 = th0 * th0, u1 = th1 * th1, u2 = th2 * th2, u3 = th3 * th3;

        const v2h c3 = splath(-0.00120984f), c2h = splath(0.02603622f);
        const v2h c1 = splath(-0.20598500f), c0h = splath(0.95858467f);
        v2h P0 = pkfmah(c3, u0, c2h);
        v2h P1 = pkfmah(c3, u1, c2h);
        v2h P2 = pkfmah(c3, u2, c2h);
        v2h P3 = pkfmah(c3, u3, c2h);
        P0 = pkfmah(P0, u0, c1);
        P1 = pkfmah(P1, u1, c1);
        P2 = pkfmah(P2, u2, c1);
        P3 = pkfmah(P3, u3, c1);
        P0 = pkfmah(P0, u0, c0h);
        P1 = pkfmah(P1, u1, c0h);
        P2 = pkfmah(P2, u2, c0h);
        P3 = pkfmah(P3, u3, c0h);

        v2h h0 = th0 * P0, h1 = th1 * P1, h2 = th2 * P2, h3 = th3 * P3;

        // pairwise cvt: one v_cvt_pkrtz per (j,j+1,m); lo/hi broadcast -> op_sel
        const v2h pA0 = cvt_pk(w2a.x, w2a.w);   // m0: j0, j1
        const v2h pA1 = cvt_pk(w2a.y, w2b.x);   // m1: j0, j1
        const v2h pA2 = cvt_pk(w2a.z, w2b.y);   // m2: j0, j1
        const v2h pB0 = cvt_pk(w2b.z, w2c.y);   // m0: j2, j3
        const v2h pB1 = cvt_pk(w2b.w, w2c.z);   // m1: j2, j3
        const v2h pB2 = cvt_pk(w2c.x, w2c.w);   // m2: j2, j3

        acc0 = pkfmah(h0, blo(pA0), acc0);
        acc1 = pkfmah(h0, blo(pA1), acc1);
        acc2 = pkfmah(h0, blo(pA2), acc2);
        acc0 = pkfmah(h1, bhi(pA0), acc0);
        acc1 = pkfmah(h1, bhi(pA1), acc1);
        acc2 = pkfmah(h1, bhi(pA2), acc2);
        acc0 = pkfmah(h2, blo(pB0), acc0);
        acc1 = pkfmah(h2, blo(pB1), acc1);
        acc2 = pkfmah(h2, blo(pB2), acc2);
        acc0 = pkfmah(h3, bhi(pB0), acc0);
        acc1 = pkfmah(h3, bhi(pB1), acc1);
        acc2 = pkfmah(h3, bhi(pB2), acc2);
    }

    // Epilogue constants from this wave's LDS slot (broadcast reads; same-wave
    // producer => lgkmcnt ordering, no barrier).
    const float* __restrict__ smc = smw[wid];
    float A[9], U[9], Wn[9], H3c[9], bl2[3], cv[3];
#pragma unroll
    for (int i = 0; i < 9; ++i) { A[i] = smc[i]; U[i] = smc[9 + i]; Wn[i] = smc[18 + i]; H3c[i] = smc[33 + i]; }
#pragma unroll
    for (int i = 0; i < 3; ++i) { bl2[i] = smc[27 + i]; cv[i] = smc[30 + i]; }

    // ---- Epilogue, packed over the 2 points (v2f = {p0, p1}) ----
    v2f sm0, sm1, sm2;   // raw seq sums (pre-H3)
    sm0.x = (float)acc0.x; sm0.y = (float)acc0.y;
    sm1.x = (float)acc1.x; sm1.y = (float)acc1.y;
    sm2.x = (float)acc2.x; sm2.y = (float)acc2.y;

    // lab2rgb(x)
    const v2f fy = (xs2[0] + splat(16.0f)) * splat(1.0f / 116.0f);
    const v2f fx = pkfma(xs2[1], splat( 0.002f), fy);
    const v2f fz = pkfma(xs2[2], splat(-0.005f), fy);
    const v2f f3x = fx * fx * fx, f3y = fy * fy * fy, f3z = fz * fz * fz;
    const v2f tx = selgt(f3x, LAB_EPS, f3x, (fx - splat(F16_116)) * splat(1.0f / 7.787f));
    const v2f ty = selgt(f3y, LAB_EPS, f3y, (fy - splat(F16_116)) * splat(1.0f / 7.787f));
    const v2f tz = selgt(f3z, LAB_EPS, f3z, (fz - splat(F16_116)) * splat(1.0f / 7.787f));
    const v2f X = tx * splat(0.95047f), Y = ty, Z = tz * splat(1.08883f);
    v2f linv[3];
    linv[0] = pkfma(X, splat( 3.2404542f), pkfma(Y, splat(-1.5371385f), Z * splat(-0.4985314f)));
    linv[1] = pkfma(X, splat(-0.9692660f), pkfma(Y, splat( 1.8760108f), Z * splat( 0.0415560f)));
    linv[2] = pkfma(X, splat( 0.0556434f), pkfma(Y, splat(-0.2040259f), Z * splat( 1.0572252f)));
    v2f lg[3];
#pragma unroll
    for (int c = 0; c < 3; ++c) {
        const v2f cc = linv[c];
        const v2f lo = cc * splat(12.92f);
        const v2f hi = pkfma(pexp2(plog2(pmax(cc, 0.0031308f)) * splat(1.0f / 2.4f)),
                             splat(1.055f), splat(-0.055f));
        lg[c] = plog2(selle(cc, 0.0031308f, lo, hi));
    }
    // r10 = exp2(lg@Wn + bl2); srgb_to_linear(r10)
    v2f lin2[3];
#pragma unroll
    for (int c = 0; c < 3; ++c) {
        const v2f e   = pkfma(lg[0], splat(Wn[c]),
                        pkfma(lg[1], splat(Wn[3 + c]),
                        pkfma(lg[2], splat(Wn[6 + c]), splat(bl2[c]))));
        const v2f r10 = pexp2(e);
        const v2f lo  = r10 * splat(1.0f / 12.92f);
        const v2f base = (pmax(r10, 0.04045f) + splat(0.055f)) * splat(1.0f / 1.055f);
        const v2f hi  = pexp2(plog2(base) * splat(2.4f));
        lin2[c] = selle(r10, 0.04045f, lo, hi);
    }
    // rgb2lab -> f-values
    const v2f X2 = pkfma(lin2[0], splat(0.412453f), pkfma(lin2[1], splat(0.357580f), lin2[2] * splat(0.180423f))) * splat(1.0f / 0.95047f);
    const v2f Y2 = pkfma(lin2[0], splat(0.212671f), pkfma(lin2[1], splat(0.715160f), lin2[2] * splat(0.072169f)));
    const v2f Z2 = pkfma(lin2[0], splat(0.019334f), pkfma(lin2[1], splat(0.119193f), lin2[2] * splat(0.950227f))) * splat(1.0f / 1.08883f);
    const v2f fX = selgt(X2, LAB_EPS, pexp2(plog2(pmax(X2, LAB_EPS)) * splat(1.0f / 3.0f)), pkfma(X2, splat(7.787f), splat(F16_116)));
    const v2f fY = selgt(Y2, LAB_EPS, pexp2(plog2(pmax(Y2, LAB_EPS)) * splat(1.0f / 3.0f)), pkfma(Y2, splat(7.787f), splat(F16_116)));
    const v2f fZ = selgt(Z2, LAB_EPS, pexp2(plog2(pmax(Z2, LAB_EPS)) * splat(1.0f / 3.0f)), pkfma(Z2, splat(7.787f), splat(F16_116)));
    // final combine: cv + x@A + s@H3 + f@U
    v2f o[3];
#pragma unroll
    for (int c = 0; c < 3; ++c) {
        v2f oc = splat(cv[c]);
        oc = pkfma(xs2[0], splat(A[c]),       oc);
        oc = pkfma(xs2[1], splat(A[3 + c]),   oc);
        oc = pkfma(xs2[2], splat(A[6 + c]),   oc);
        oc = pkfma(sm0,    splat(H3c[c]),     oc);
        oc = pkfma(sm1,    splat(H3c[3 + c]), oc);
        oc = pkfma(sm2,    splat(H3c[6 + c]), oc);
        oc = pkfma(fX,     splat(U[c]),       oc);
        oc = pkfma(fY,     splat(U[3 + c]),   oc);
        oc = pkfma(fZ,     splat(U[6 + c]),   oc);
        o[c] = oc;
    }

    float2* op = reinterpret_cast<float2*>(out) + (size_t)g * 3;
    op[0] = make_float2(o[0].x, o[1].x);
    op[1] = make_float2(o[2].x, o[0].y);
    op[2] = make_float2(o[1].y, o[2].y);
}

extern "C" void kernel_launch(void* const* d_in, const int* in_sizes, int n_in,
                              void* d_out, int out_size, void* d_ws, size_t ws_size,
                              hipStream_t stream)
{
    const float* x       = (const float*)d_in[0];
    const float* w_seq1  = (const float*)d_in[1];
    const float* b_seq1  = (const float*)d_in[2];
    const float* w_seq2  = (const float*)d_in[3];
    const float* b_seq2  = (const float*)d_in[4];
    const float* w_lin   = (const float*)d_in[5];
    const float* b_lin   = (const float*)d_in[6];
    const float* w_comb  = (const float*)d_in[7];
    const float* b_comb  = (const float*)d_in[8];
    const float* w_logd  = (const float*)d_in[9];
    const float* b_logd  = (const float*)d_in[10];
    const float* w_final = (const float*)d_in[11];
    const float* b_final = (const float*)d_in[12];
    float* outp = (float*)d_out;

    const int n = in_sizes[0] / 3;            // 2,097,152 points
    const int threads = 256;
    const int total_threads = (n + 1) / 2;    // 2 points per thread
    const int blocks = (total_threads + threads - 1) / threads;

    fused_kernel<<<blocks, threads, 0, stream>>>(
        x, w_seq1, b_seq1, w_seq2, b_seq2, w_lin, b_lin, w_comb, b_comb,
        w_logd, b_logd, w_final, b_final, outp, n);
}

// Round 10
// 135.836 us; speedup vs baseline: 1.0513x; 1.0236x over previous
//
#include <hip/hip_runtime.h>

typedef float    v2f __attribute__((ext_vector_type(2)));
typedef _Float16 v2h __attribute__((ext_vector_type(2)));

__device__ __forceinline__ float fexp2(float x) { return __builtin_amdgcn_exp2f(x); }
__device__ __forceinline__ float flog2(float x) { return __builtin_amdgcn_logf(x); }
__device__ __forceinline__ v2f  splat(float s) { v2f v; v.x = s; v.y = s; return v; }
__device__ __forceinline__ v2f  pkfma(v2f a, v2f b, v2f c) { return __builtin_elementwise_fma(a, b, c); }
__device__ __forceinline__ v2h  splath(float s) { v2h v; v.x = (_Float16)s; v.y = (_Float16)s; return v; }
__device__ __forceinline__ v2h  pkfmah(v2h a, v2h b, v2h c) { return __builtin_elementwise_fma(a, b, c); }
__device__ __forceinline__ v2h  cvt_pk(float a, float b) {
    return __builtin_bit_cast(v2h, __builtin_amdgcn_cvt_pkrtz(a, b));
}
// packed-pair helpers (elementwise over the two points)
__device__ __forceinline__ v2f pexp2(v2f e) { v2f r; r.x = fexp2(e.x); r.y = fexp2(e.y); return r; }
__device__ __forceinline__ v2f plog2(v2f e) { v2f r; r.x = flog2(e.x); r.y = flog2(e.y); return r; }
__device__ __forceinline__ v2f selgt(v2f c, float thr, v2f a, v2f b) {
    v2f r; r.x = c.x > thr ? a.x : b.x; r.y = c.y > thr ? a.y : b.y; return r;
}
__device__ __forceinline__ v2f selle(v2f c, float thr, v2f a, v2f b) {
    v2f r; r.x = c.x <= thr ? a.x : b.x; r.y = c.y <= thr ? a.y : b.y; return r;
}
__device__ __forceinline__ v2f pmax(v2f a, float s) { return __builtin_elementwise_max(a, splat(s)); }

#define LAB_EPS 0.008856f
#define F16_116 0.13793103448275862f   // 16/116
#define LOG2_10 3.3219280948873623f

// ---------------------------------------------------------------------------
// r6 structure (best harness: 133.07) with its one identified defect fixed.
// Single launch. Hidden loop: wsa via s_load from raw w_seq1/b_seq1 (uniform
// float4), wsb PRE-FOLDED into LDS (no in-loop cvt — the 2.5us r7 tax).
// PROLOGUE SPLIT (the fix): threads 0-63 fold wsbL in parallel; threads
// 64-72 fold the 33 epilogue consts in parallel (r7's verified 9-thread
// code) — removes r6's thread-0 ~150-op serial chain from the barrier path.
// ---------------------------------------------------------------------------
__global__ __launch_bounds__(256) void fused_kernel(
    const float* __restrict__ x,
    const float* __restrict__ w_seq1, const float* __restrict__ b_seq1,
    const float* __restrict__ w_seq2, const float* __restrict__ b_seq2,
    const float* __restrict__ w_lin,  const float* __restrict__ b_lin,
    const float* __restrict__ w_comb, const float* __restrict__ b_comb,
    const float* __restrict__ w_logd, const float* __restrict__ b_logd,
    const float* __restrict__ w_final,const float* __restrict__ b_final,
    float* __restrict__ out, int n)
{
    __shared__ uint4 wsbL[64];    // j: {pk(w2p_j0), pk(w2p_j1), pk(w2p_j2), 0} half2-replicated
    __shared__ float smlds[33];   // A[9], U[9], Wn[9], bl2[3], cv[3]

    const int tid = threadIdx.x;
    if (tid < 64) {
        // ---- wsb fold: 64 threads in parallel ----
        const int j = tid;
        float H3[9];
#pragma unroll
        for (int i = 0; i < 3; ++i)
#pragma unroll
            for (int c = 0; c < 3; ++c) {
                float h = 0.f;
                for (int m = 0; m < 3; ++m) h += w_comb[(i + 3) * 3 + m] * w_final[m * 3 + c];
                H3[i * 3 + c] = h;
            }
        const float w0 = w_seq2[j * 3 + 0], w1 = w_seq2[j * 3 + 1], w2 = w_seq2[j * 3 + 2];
        const float wp0 = w0 * H3[0] + w1 * H3[3] + w2 * H3[6];
        const float wp1 = w0 * H3[1] + w1 * H3[4] + w2 * H3[7];
        const float wp2 = w0 * H3[2] + w1 * H3[5] + w2 * H3[8];
        uint4 wb;
        wb.x = __builtin_bit_cast(unsigned, cvt_pk(wp0, wp0));
        wb.y = __builtin_bit_cast(unsigned, cvt_pk(wp1, wp1));
        wb.z = __builtin_bit_cast(unsigned, cvt_pk(wp2, wp2));
        wb.w = 0u;
        wsbL[j] = wb;
    } else if (tid < 73) {
        // ---- epilogue consts: 9 threads in parallel (concurrent with wave 0) ----
        const int lane = tid - 64;
        const int kk = lane / 3, c = lane - kk * 3;
        const float wf0 = w_final[c], wf3 = w_final[3 + c], wf6 = w_final[6 + c];
        const float Gc0 = w_comb[0] * wf0 + w_comb[1] * wf3 + w_comb[2] * wf6;
        const float Gc1 = w_comb[3] * wf0 + w_comb[4] * wf3 + w_comb[5] * wf6;
        const float Gc2 = w_comb[6] * wf0 + w_comb[7] * wf3 + w_comb[8] * wf6;
        smlds[lane] = w_lin[kk * 3 + 0] * Gc0 + w_lin[kk * 3 + 1] * Gc1 + w_lin[kk * 3 + 2] * Gc2; // A
        const float wb0 = w_final[9 + c], wb1 = w_final[12 + c], wb2 = w_final[15 + c];
        smlds[9 + lane] = (kk == 0) ? 500.0f * wb1
                        : (kk == 1) ? 116.0f * wb0 - 500.0f * wb1 + 200.0f * wb2
                                    : -200.0f * wb2;                                               // U
        smlds[18 + lane] = -w_logd[lane];                                                          // Wn
        if (kk == 0) {   // lane < 3, c == lane
            smlds[27 + c] = LOG2_10 * b_logd[c];                                                   // bl2
            const float H30 = w_comb[ 9] * wf0 + w_comb[10] * wf3 + w_comb[11] * wf6;
            const float H31 = w_comb[12] * wf0 + w_comb[13] * wf3 + w_comb[14] * wf6;
            const float H32 = w_comb[15] * wf0 + w_comb[16] * wf3 + w_comb[17] * wf6;
            float s = b_final[c] - 16.0f * wb0;
            s += b_lin[0] * Gc0 + b_lin[1] * Gc1 + b_lin[2] * Gc2;
            s += b_seq2[0] * H30 + b_seq2[1] * H31 + b_seq2[2] * H32;
            s += b_comb[0] * wf0 + b_comb[1] * wf3 + b_comb[2] * wf6;
            smlds[30 + c] = s;                                                                     // cv
        }
    }
    __syncthreads();

    const int g = blockIdx.x * blockDim.x + tid;
    if (g * 2 >= n) return;

    // 2 points = 6 floats = 3 float2 (coalesced 8B loads)
    const float2* xin = reinterpret_cast<const float2*>(x) + (size_t)g * 3;
    const float2 v0 = xin[0], v1 = xin[1], v2 = xin[2];
    // p0 = {v0.x, v0.y, v1.x}, p1 = {v1.y, v2.x, v2.y}
    v2f xs2[3];
    xs2[0].x = v0.x; xs2[0].y = v1.y;
    xs2[1].x = v0.y; xs2[1].y = v2.x;
    xs2[2].x = v1.x; xs2[2].y = v2.y;

    v2h acc0 = splath(0.f), acc1 = splath(0.f), acc2 = splath(0.f);

    // w_seq1 rows are contiguous in j: row i at float4 offset i*16 + j/4.
    const float4* __restrict__ w1v = reinterpret_cast<const float4*>(w_seq1);
    const float4* __restrict__ b1v = reinterpret_cast<const float4*>(b_seq1);

    // Hidden layer, stage-major 4-wide batches; wsa via s_load (uniform),
    // wsb via broadcast ds_read_b128 batched 4-ahead.
#pragma unroll 2
    for (int j0 = 0; j0 < 64; j0 += 4) {
        const int q = j0 >> 2;
        const float4 wr0 = w1v[q];         // w_seq1[0][j0..j0+3]
        const float4 wr1 = w1v[16 + q];    // w_seq1[1][...]
        const float4 wr2 = w1v[32 + q];    // w_seq1[2][...]
        const float4 wrb = b1v[q];         // b_seq1[...]
        const uint4 wb0 = wsbL[j0 + 0], wb1 = wsbL[j0 + 1], wb2 = wsbL[j0 + 2], wb3 = wsbL[j0 + 3];

        v2f t0 = pkfma(xs2[0], splat(wr0.x), pkfma(xs2[1], splat(wr1.x), pkfma(xs2[2], splat(wr2.x), splat(wrb.x))));
        v2f t1 = pkfma(xs2[0], splat(wr0.y), pkfma(xs2[1], splat(wr1.y), pkfma(xs2[2], splat(wr2.y), splat(wrb.y))));
        v2f t2 = pkfma(xs2[0], splat(wr0.z), pkfma(xs2[1], splat(wr1.z), pkfma(xs2[2], splat(wr2.z), splat(wrb.z))));
        v2f t3 = pkfma(xs2[0], splat(wr0.w), pkfma(xs2[1], splat(wr1.w), pkfma(xs2[2], splat(wr2.w), splat(wrb.w))));

        v2h th0 = cvt_pk(t0.x, t0.y);
        v2h th1 = cvt_pk(t1.x, t1.y);
        v2h th2 = cvt_pk(t2.x, t2.y);
        v2h th3 = cvt_pk(t3.x, t3.y);

        const v2h hi3 = splath(3.0f), lo3 = splath(-3.0f);
        th0 = __builtin_elementwise_min(__builtin_elementwise_max(th0, lo3), hi3);
        th1 = __builtin_elementwise_min(__builtin_elementwise_max(th1, lo3), hi3);
        th2 = __builtin_elementwise_min(__builtin_elementwise_max(th2, lo3), hi3);
        th3 = __builtin_elementwise_min(__builtin_elementwise_max(th3, lo3), hi3);

        v2h u0 = th0 * th0, u1 = th1 * th1, u2 = th2 * th2, u3 = th3 * th3;

        const v2h c3 = splath(-0.00120984f), c2h = splath(0.02603622f);
        const v2h c1 = splath(-0.20598500f), c0h = splath(0.95858467f);
        v2h P0 = pkfmah(c3, u0, c2h);
        v2h P1 = pkfmah(c3, u1, c2h);
        v2h P2 = pkfmah(c3, u2, c2h);
        v2h P3 = pkfmah(c3, u3, c2h);
        P0 = pkfmah(P0, u0, c1);
        P1 = pkfmah(P1, u1, c1);
        P2 = pkfmah(P2, u2, c1);
        P3 = pkfmah(P3, u3, c1);
        P0 = pkfmah(P0, u0, c0h);
        P1 = pkfmah(P1, u1, c0h);
        P2 = pkfmah(P2, u2, c0h);
        P3 = pkfmah(P3, u3, c0h);

        v2h h0 = th0 * P0, h1 = th1 * P1, h2 = th2 * P2, h3 = th3 * P3;

        acc0 = pkfmah(h0, __builtin_bit_cast(v2h, wb0.x), acc0);
        acc1 = pkfmah(h0, __builtin_bit_cast(v2h, wb0.y), acc1);
        acc2 = pkfmah(h0, __builtin_bit_cast(v2h, wb0.z), acc2);
        acc0 = pkfmah(h1, __builtin_bit_cast(v2h, wb1.x), acc0);
        acc1 = pkfmah(h1, __builtin_bit_cast(v2h, wb1.y), acc1);
        acc2 = pkfmah(h1, __builtin_bit_cast(v2h, wb1.z), acc2);
        acc0 = pkfmah(h2, __builtin_bit_cast(v2h, wb2.x), acc0);
        acc1 = pkfmah(h2, __builtin_bit_cast(v2h, wb2.y), acc1);
        acc2 = pkfmah(h2, __builtin_bit_cast(v2h, wb2.z), acc2);
        acc0 = pkfmah(h3, __builtin_bit_cast(v2h, wb3.x), acc0);
        acc1 = pkfmah(h3, __builtin_bit_cast(v2h, wb3.y), acc1);
        acc2 = pkfmah(h3, __builtin_bit_cast(v2h, wb3.z), acc2);
    }

    // Epilogue constants from LDS (broadcast reads, once).
    float A[9], U[9], Wn[9], bl2[3], cv[3];
#pragma unroll
    for (int i = 0; i < 9; ++i) { A[i] = smlds[i]; U[i] = smlds[9 + i]; Wn[i] = smlds[18 + i]; }
#pragma unroll
    for (int i = 0; i < 3; ++i) { bl2[i] = smlds[27 + i]; cv[i] = smlds[30 + i]; }

    // ---- Epilogue, packed over the 2 points (v2f = {p0, p1}) ----
    v2f sq0, sq1, sq2;
    sq0.x = (float)acc0.x; sq0.y = (float)acc0.y;
    sq1.x = (float)acc1.x; sq1.y = (float)acc1.y;
    sq2.x = (float)acc2.x; sq2.y = (float)acc2.y;

    // lab2rgb(x)
    const v2f fy = (xs2[0] + splat(16.0f)) * splat(1.0f / 116.0f);
    const v2f fx = pkfma(xs2[1], splat( 0.002f), fy);
    const v2f fz = pkfma(xs2[2], splat(-0.005f), fy);
    const v2f f3x = fx * fx * fx, f3y = fy * fy * fy, f3z = fz * fz * fz;
    const v2f tx = selgt(f3x, LAB_EPS, f3x, (fx - splat(F16_116)) * splat(1.0f / 7.787f));
    const v2f ty = selgt(f3y, LAB_EPS, f3y, (fy - splat(F16_116)) * splat(1.0f / 7.787f));
    const v2f tz = selgt(f3z, LAB_EPS, f3z, (fz - splat(F16_116)) * splat(1.0f / 7.787f));
    const v2f X = tx * splat(0.95047f), Y = ty, Z = tz * splat(1.08883f);
    v2f linv[3];
    linv[0] = pkfma(X, splat( 3.2404542f), pkfma(Y, splat(-1.5371385f), Z * splat(-0.4985314f)));
    linv[1] = pkfma(X, splat(-0.9692660f), pkfma(Y, splat( 1.8760108f), Z * splat( 0.0415560f)));
    linv[2] = pkfma(X, splat( 0.0556434f), pkfma(Y, splat(-0.2040259f), Z * splat( 1.0572252f)));
    v2f lg[3];
#pragma unroll
    for (int c = 0; c < 3; ++c) {
        const v2f cc = linv[c];
        const v2f lo = cc * splat(12.92f);
        const v2f hi = pkfma(pexp2(plog2(pmax(cc, 0.0031308f)) * splat(1.0f / 2.4f)),
                             splat(1.055f), splat(-0.055f));
        lg[c] = plog2(selle(cc, 0.0031308f, lo, hi));
    }
    // r10 = exp2(lg@Wn + bl2); srgb_to_linear(r10)
    v2f lin2[3];
#pragma unroll
    for (int c = 0; c < 3; ++c) {
        const v2f e   = pkfma(lg[0], splat(Wn[c]),
                        pkfma(lg[1], splat(Wn[3 + c]),
                        pkfma(lg[2], splat(Wn[6 + c]), splat(bl2[c]))));
        const v2f r10 = pexp2(e);
        const v2f lo  = r10 * splat(1.0f / 12.92f);
        const v2f base = (pmax(r10, 0.04045f) + splat(0.055f)) * splat(1.0f / 1.055f);
        const v2f hi  = pexp2(plog2(base) * splat(2.4f));
        lin2[c] = selle(r10, 0.04045f, lo, hi);
    }
    // rgb2lab -> f-values
    const v2f X2 = pkfma(lin2[0], splat(0.412453f), pkfma(lin2[1], splat(0.357580f), lin2[2] * splat(0.180423f))) * splat(1.0f / 0.95047f);
    const v2f Y2 = pkfma(lin2[0], splat(0.212671f), pkfma(lin2[1], splat(0.715160f), lin2[2] * splat(0.072169f)));
    const v2f Z2 = pkfma(lin2[0], splat(0.019334f), pkfma(lin2[1], splat(0.119193f), lin2[2] * splat(0.950227f))) * splat(1.0f / 1.08883f);
    const v2f fX = selgt(X2, LAB_EPS, pexp2(plog2(pmax(X2, LAB_EPS)) * splat(1.0f / 3.0f)), pkfma(X2, splat(7.787f), splat(F16_116)));
    const v2f fY = selgt(Y2, LAB_EPS, pexp2(plog2(pmax(Y2, LAB_EPS)) * splat(1.0f / 3.0f)), pkfma(Y2, splat(7.787f), splat(F16_116)));
    const v2f fZ = selgt(Z2, LAB_EPS, pexp2(plog2(pmax(Z2, LAB_EPS)) * splat(1.0f / 3.0f)), pkfma(Z2, splat(7.787f), splat(F16_116)));
    // final combine (U-folded; acc already includes H3)
    v2f o[3];
#pragma unroll
    for (int c = 0; c < 3; ++c) {
        v2f oc = splat(cv[c]);
        oc = pkfma(xs2[0], splat(A[c]),     oc);
        oc = pkfma(xs2[1], splat(A[3 + c]), oc);
        oc = pkfma(xs2[2], splat(A[6 + c]), oc);
        oc = oc + (c == 0 ? sq0 : (c == 1 ? sq1 : sq2));
        oc = pkfma(fX, splat(U[c]),     oc);
        oc = pkfma(fY, splat(U[3 + c]), oc);
        oc = pkfma(fZ, splat(U[6 + c]), oc);
        o[c] = oc;
    }

    float2* op = reinterpret_cast<float2*>(out) + (size_t)g * 3;
    op[0] = make_float2(o[0].x, o[1].x);
    op[1] = make_float2(o[2].x, o[0].y);
    op[2] = make_float2(o[1].y, o[2].y);
}

extern "C" void kernel_launch(void* const* d_in, const int* in_sizes, int n_in,
                              void* d_out, int out_size, void* d_ws, size_t ws_size,
                              hipStream_t stream)
{
    const float* x       = (const float*)d_in[0];
    const float* w_seq1  = (const float*)d_in[1];
    const float* b_seq1  = (const float*)d_in[2];
    const float* w_seq2  = (const float*)d_in[3];
    const float* b_seq2  = (const float*)d_in[4];
    const float* w_lin   = (const float*)d_in[5];
    const float* b_lin   = (const float*)d_in[6];
    const float* w_comb  = (const float*)d_in[7];
    const float* b_comb  = (const float*)d_in[8];
    const float* w_logd  = (const float*)d_in[9];
    const float* b_logd  = (const float*)d_in[10];
    const float* w_final = (const float*)d_in[11];
    const float* b_final = (const float*)d_in[12];
    float* outp = (float*)d_out;

    const int n = in_sizes[0] / 3;            // 2,097,152 points
    const int threads = 256;
    const int total_threads = (n + 1) / 2;    // 2 points per thread
    const int blocks = (total_threads + threads - 1) / threads;

    fused_kernel<<<blocks, threads, 0, stream>>>(
        x, w_seq1, b_seq1, w_seq2, b_seq2, w_lin, b_lin, w_comb, b_comb,
        w_logd, b_logd, w_final, b_final, outp, n);
}